// Round 6
// baseline (1945.088 us; speedup 1.0000x reference)
//
#include <hip/hip_runtime.h>
#include <math.h>

// ODE-RNN encoder, fully fused: one 64-lane wave per batch sample.
// Time = per-sample serial chain latency. This round: weights are FORCED
// register-resident (opaque asm identity defeats rematerialization — r3/r5
// showed the compiler re-loading loop-invariant weights every MLP eval,
// VGPR_Count 120/132). No LDS weight arrays (r5's 1.17e8 bank-conflict
// cycles came from per-lane distinct-row weight reads). LDS is only used
// for uniform-address activation broadcasts (conflict-free) and x staging.
//  - FSAL: k1 of next Tsit5 iter = k7 on accept (bit-exact by determinism).
//  - 16-wide gathers (L0, GRU) via v_readlane on lane-replicated state.
//  - No __syncthreads in hot loop: single-wave block, same-wave DS ops are
//    in program order; asm memory fences stop compiler reordering.
// All dot summation orders are bit-identical to the round-3 passing kernel
// (absmax 0.0): t0..t7 map to the old packed accumulators' .x/.y lanes.

namespace {
constexpr int LSEQ = 256;

__device__ __forceinline__ float RL(float v, int k) {   // broadcast lane k
    return __uint_as_float(__builtin_amdgcn_readlane(__float_as_uint(v), k));
}
#define LDSFENCE() asm volatile("" ::: "memory")
#define KEEPF(x)   asm volatile("" : "+v"(x))   // opaque: forbids remat/fold

__device__ __forceinline__ float tanh_f(float x) {
    float e = exp2f(x * 2.8853900817779268f);
    return 1.0f - 2.0f * __builtin_amdgcn_rcpf(e + 1.0f);
}
__device__ __forceinline__ float sigm_f(float x) {
    return __builtin_amdgcn_rcpf(1.0f + exp2f(x * -1.4426950408889634f));
}
} // namespace

// 64-wide dot vs register weight row; act reads are uniform LDS broadcasts.
// t0..t7 reproduce r3's packed accumulators: tK takes elements c == K (mod 8);
// result = ((t0+t2)+(t4+t6)) + ((t1+t3)+(t5+t7))  ==  old (a0+a1)+(a2+a3),.x+.y
#define DOT64R(res, warr, act, bias)                                   \
    do {                                                               \
        float t0 = (bias), t1 = 0.f, t2 = 0.f, t3 = 0.f,               \
              t4 = 0.f, t5 = 0.f, t6 = 0.f, t7 = 0.f;                  \
        _Pragma("unroll")                                              \
        for (int q = 0; q < 16; q += 2) {                              \
            float4 u = (act)[q];                                       \
            t0 = fmaf(warr[4*q+0], u.x, t0);                           \
            t1 = fmaf(warr[4*q+1], u.y, t1);                           \
            t2 = fmaf(warr[4*q+2], u.z, t2);                           \
            t3 = fmaf(warr[4*q+3], u.w, t3);                           \
            float4 v = (act)[q+1];                                     \
            t4 = fmaf(warr[4*q+4], v.x, t4);                           \
            t5 = fmaf(warr[4*q+5], v.y, t5);                           \
            t6 = fmaf(warr[4*q+6], v.z, t6);                           \
            t7 = fmaf(warr[4*q+7], v.w, t7);                           \
        }                                                              \
        res = ((t0 + t2) + (t4 + t6)) + ((t1 + t3) + (t5 + t7));       \
    } while (0)

// 16-wide dot (L3 split-k chunk); uK takes elements c == K (mod 4);
// result = (u0+u2)+(u1+u3)  ==  old packed (a0+a1).x + .y
#define DOT16R(res, warr, act)                                         \
    do {                                                               \
        float u0 = 0.f, u1 = 0.f, u2 = 0.f, u3 = 0.f;                  \
        _Pragma("unroll")                                              \
        for (int q = 0; q < 4; ++q) {                                  \
            float4 u = (act)[q];                                       \
            u0 = fmaf(warr[4*q+0], u.x, u0);                           \
            u1 = fmaf(warr[4*q+1], u.y, u1);                           \
            u2 = fmaf(warr[4*q+2], u.z, u2);                           \
            u3 = fmaf(warr[4*q+3], u.w, u3);                           \
        }                                                              \
        res = (u0 + u2) + (u1 + u3);                                   \
    } while (0)

extern "C" __global__ void __launch_bounds__(64, 1)
odern_kernel(const float* __restrict__ x_seq,
             const float* __restrict__ W0, const float* __restrict__ b0,
             const float* __restrict__ W1, const float* __restrict__ b1,
             const float* __restrict__ W2, const float* __restrict__ b2,
             const float* __restrict__ W3, const float* __restrict__ b3,
             const float* __restrict__ Wih, const float* __restrict__ Whh,
             const float* __restrict__ bih, const float* __restrict__ bn,
             const float* __restrict__ Wp, const float* __restrict__ bp,
             float* __restrict__ out)
{
    const int j   = threadIdx.x;      // 0..63
    const int b   = blockIdx.x;       // sample
    const int i16 = j & 15;           // owned y-component (replicated x4)

    __shared__ __align__(16) float s_hA[64];
    __shared__ __align__(16) float s_hB[64];
    __shared__ __align__(16) float s_x[2 * LSEQ];
    __shared__ float s_ig[48];
    __shared__ float s_hg[48];

    // ---------------- x row -> LDS (once) ----------------
    {
        const float4* xv = (const float4*)(x_seq + (long)b * (2 * LSEQ));
        float4 t0 = xv[j];
        float4 t1 = xv[j + 64];
        ((float4*)s_x)[j]      = t0;
        ((float4*)s_x)[j + 64] = t1;
    }

    // ---------------- weights -> registers, PINNED ----------------
    float w0s[16], w1s[64], w2s[64], w3s[16], whs[16];
    {
        const float4* p = (const float4*)(W0 + j * 16);
        #pragma unroll
        for (int q = 0; q < 4; ++q) { float4 u = p[q];
            w0s[4*q]=u.x; w0s[4*q+1]=u.y; w0s[4*q+2]=u.z; w0s[4*q+3]=u.w; }
    }
    {
        const float4* p = (const float4*)(W1 + j * 64);
        #pragma unroll
        for (int q = 0; q < 16; ++q) { float4 u = p[q];
            w1s[4*q]=u.x; w1s[4*q+1]=u.y; w1s[4*q+2]=u.z; w1s[4*q+3]=u.w; }
    }
    {
        const float4* p = (const float4*)(W2 + j * 64);
        #pragma unroll
        for (int q = 0; q < 16; ++q) { float4 u = p[q];
            w2s[4*q]=u.x; w2s[4*q+1]=u.y; w2s[4*q+2]=u.z; w2s[4*q+3]=u.w; }
    }
    {
        const float4* p = (const float4*)(W3 + i16 * 64 + (j >> 4) * 16);
        #pragma unroll
        for (int q = 0; q < 4; ++q) { float4 u = p[q];
            w3s[4*q]=u.x; w3s[4*q+1]=u.y; w3s[4*q+2]=u.z; w3s[4*q+3]=u.w; }
    }
    const int jg = (j < 48) ? j : 47;   // clamp for 48-row GRU mats
    {
        const float4* p = (const float4*)(Whh + jg * 16);
        #pragma unroll
        for (int q = 0; q < 4; ++q) { float4 u = p[q];
            whs[4*q]=u.x; whs[4*q+1]=u.y; whs[4*q+2]=u.z; whs[4*q+3]=u.w; }
    }
    float wih0 = Wih[jg * 2], wih1 = Wih[jg * 2 + 1], bihj = bih[jg];
    float bs0 = b0[j], bs1 = b1[j], bs2 = b2[j];
    float b3r = b3[i16], bnr = bn[i16], wpr = Wp[i16];

    // Opaque identity on every loop-invariant value: the compiler can no
    // longer rematerialize the loads inside the hot loop -> true residency.
    #pragma unroll
    for (int i = 0; i < 16; ++i) KEEPF(w0s[i]);
    #pragma unroll
    for (int i = 0; i < 64; ++i) KEEPF(w1s[i]);
    #pragma unroll
    for (int i = 0; i < 64; ++i) KEEPF(w2s[i]);
    #pragma unroll
    for (int i = 0; i < 16; ++i) KEEPF(w3s[i]);
    #pragma unroll
    for (int i = 0; i < 16; ++i) KEEPF(whs[i]);
    KEEPF(wih0); KEEPF(wih1); KEEPF(bihj);
    KEEPF(bs0);  KEEPF(bs1);  KEEPF(bs2);
    KEEPF(b3r);  KEEPF(bnr);  KEEPF(wpr);

    __syncthreads();   // one-time; hot loop is barrier-free

    // MLP eval; ys is lane-replicated (lane k<16 holds component k).
    auto mlp = [&](float ys) -> float {
        // L0: 16 -> 64 via readlane broadcasts (no LDS round-trip).
        float t0 = bs0, t1 = 0.f, t2 = 0.f, t3 = 0.f;
        #pragma unroll
        for (int k = 0; k < 16; k += 4) {
            t0 = fmaf(w0s[k + 0], RL(ys, k + 0), t0);
            t1 = fmaf(w0s[k + 1], RL(ys, k + 1), t1);
            t2 = fmaf(w0s[k + 2], RL(ys, k + 2), t2);
            t3 = fmaf(w0s[k + 3], RL(ys, k + 3), t3);
        }
        float a = tanh_f((t0 + t2) + (t1 + t3));
        s_hA[j] = a;
        LDSFENCE();                 // same-wave DS in-order; stop IR reorder
        float d1; DOT64R(d1, w1s, (const float4*)s_hA, bs1);
        float a1 = tanh_f(d1);
        s_hB[j] = a1;
        LDSFENCE();
        float d2; DOT64R(d2, w2s, (const float4*)s_hB, bs2);
        float a2 = tanh_f(d2);
        s_hA[j] = a2;
        LDSFENCE();
        float p; DOT16R(p, w3s, (const float4*)s_hA + (j >> 4) * 4);
        p += __shfl_xor(p, 16);
        p += __shfl_xor(p, 32);
        LDSFENCE();
        return p + b3r;
    };

    // Tsit5 tableau (f32)
    const float A21 = 0.161f;
    const float A31 = -0.008480655492356989f, A32 = 0.335480655492357f;
    const float A41 = 2.8971530571054935f, A42 = -6.359448489975075f, A43 = 4.3622954328695815f;
    const float A51 = 5.325864828439257f, A52 = -11.748883564062828f, A53 = 7.4955393428898365f, A54 = -0.09249506636175525f;
    const float A61 = 5.86145544294642f, A62 = -12.92096931784711f, A63 = 8.159367898576159f, A64 = -0.071584973281401f, A65 = -0.028269050394068383f;
    const float B1 = 0.09646076681806523f, B2 = 0.01f, B3 = 0.4798896504144996f,
                B4 = 1.379008574103742f, B5 = -3.290069515436081f, B6 = 2.324710524099774f;
    const float E1 = -0.00178001105222577714f, E2 = -0.0008164344596567469f,
                E3 = 0.007880878010261995f, E4 = -0.1447110071732629f,
                E5 = 0.5823571654525552f, E6 = -0.45808210592918697f, E7 = 0.015151515151515152f;
    const float TDONE = (float)(1.0 - 1e-7);

    float y = 0.0f;                       // h0 = zeros (replicated component i16)

    #pragma unroll 1
    for (int l = 0; l < LSEQ; ++l) {
        // ---------------- adaptive Tsit5 on [0,1], dt0 = 1, FSAL ----------
        float t = 0.f, dt = 1.f;
        float k1 = mlp(y);                // first eval of this solve
        #pragma unroll 1
        for (int it = 0; it < 12; ++it) {
            if (t >= TDONE) break;        // identical to reference's frozen iters
            float dtc = fminf(dt, 1.0f - t);
            float k2 = mlp(fmaf(dtc, A21 * k1, y));
            float k3 = mlp(fmaf(dtc, A31*k1 + A32*k2, y));
            float k4 = mlp(fmaf(dtc, A41*k1 + A42*k2 + A43*k3, y));
            float k5 = mlp(fmaf(dtc, A51*k1 + A52*k2 + A53*k3 + A54*k4, y));
            float k6 = mlp(fmaf(dtc, A61*k1 + A62*k2 + A63*k3 + A64*k4 + A65*k5, y));
            float ynew = fmaf(dtc, B1*k1 + B2*k2 + B3*k3 + B4*k4 + B5*k5 + B6*k6, y);
            float k7 = mlp(ynew);
            float yerr = dtc * (E1*k1 + E2*k2 + E3*k3 + E4*k4 + E5*k5 + E6*k6 + E7*k7);
            float sc = fmaf(0.01f, fmaxf(fabsf(y), fabsf(ynew)), 1e-4f);
            float e = yerr / sc;          // keep IEEE: feeds the accept branch
            float e2 = e * e;
            e2 += __shfl_xor(e2, 1); e2 += __shfl_xor(e2, 2);
            e2 += __shfl_xor(e2, 4); e2 += __shfl_xor(e2, 8);
            float err = sqrtf(e2 * 0.0625f);
            if (err <= 1.0f) { y = ynew; t += dtc; k1 = k7; }  // FSAL
            float fac = 0.9f * exp2f(-0.2f * log2f(fmaxf(err, 1e-10f)));
            fac = fminf(fmaxf(fac, 0.2f), 10.0f);
            dt = dtc * fac;
        }
        // ---------------- GRU observation update ----------------
        float x0 = s_x[2*l], x1 = s_x[2*l + 1];
        // hg = Whh[jg,:] . y via readlane (same summation order as before)
        float h0 = 0.f, h1 = 0.f, h2 = 0.f, h3 = 0.f;
        #pragma unroll
        for (int k = 0; k < 16; k += 4) {
            h0 = fmaf(whs[k + 0], RL(y, k + 0), h0);
            h1 = fmaf(whs[k + 1], RL(y, k + 1), h1);
            h2 = fmaf(whs[k + 2], RL(y, k + 2), h2);
            h3 = fmaf(whs[k + 3], RL(y, k + 3), h3);
        }
        float hg = (h0 + h2) + (h1 + h3);
        float ig = fmaf(wih0, x0, fmaf(wih1, x1, bihj));
        if (j < 48) { s_ig[j] = ig; s_hg[j] = hg; }
        LDSFENCE();
        float ir = s_ig[i16], iz = s_ig[16+i16], in_ = s_ig[32+i16];
        float hr = s_hg[i16], hz = s_hg[16+i16], hn = s_hg[32+i16];
        float r = sigm_f(ir + hr);
        float z = sigm_f(iz + hz);
        float n = tanh_f(fmaf(r, hn + bnr, in_));
        y = n + z * (y - n);
        LDSFENCE();
    }

    // ---------------- projection: out[b] = Wp . h + bp ----------------
    float pv = y * wpr;
    pv += __shfl_xor(pv, 1); pv += __shfl_xor(pv, 2);
    pv += __shfl_xor(pv, 4); pv += __shfl_xor(pv, 8);
    if (j == 0) out[b] = pv + bp[0];
}

extern "C" void kernel_launch(void* const* d_in, const int* in_sizes, int n_in,
                              void* d_out, int out_size, void* d_ws, size_t ws_size,
                              hipStream_t stream)
{
    odern_kernel<<<dim3(512), dim3(64), 0, stream>>>(
        (const float*)d_in[0],
        (const float*)d_in[1],  (const float*)d_in[2],
        (const float*)d_in[3],  (const float*)d_in[4],
        (const float*)d_in[5],  (const float*)d_in[6],
        (const float*)d_in[7],  (const float*)d_in[8],
        (const float*)d_in[9],  (const float*)d_in[10],
        (const float*)d_in[11], (const float*)d_in[12],
        (const float*)d_in[13], (const float*)d_in[14],
        (float*)d_out);
}

// Round 8
// 1945.085 us; speedup vs baseline: 1.0000x; 1.0000x over previous
//
#include <hip/hip_runtime.h>
#include <math.h>

// ODE-RNN encoder, fully fused: one 64-lane wave per batch sample.
// Time = per-sample serial chain latency. Round-7/8 change: explicit
// amdgpu_waves_per_eu(1,1). r3/r5/r6 all landed at VGPR=120-132 (= the
// 128-VGPR / 4-waves-per-EU allocator target); r6 proved the KEEPF-pinned
// weights were spilled to scratch rather than held in registers (SGPR 112->48,
// loads gone from loop, VGPR still 120, dur worse). This kernel runs exactly
// 1 wave/SIMD by construction (512 single-wave blocks on 1024 SIMDs), so the
// occupancy target is lowered to 1 wave/EU -> RA budget 512 VGPRs -> the 176
// pinned weight floats become truly register-resident.
//  - FSAL: k1 of next Tsit5 iter = k7 on accept (bit-exact by determinism).
//  - 16-wide gathers (L0, GRU) via v_readlane on lane-replicated state.
//  - No __syncthreads in hot loop: single-wave block, same-wave DS ops are
//    in program order; asm memory fences stop compiler reordering.
// All dot summation orders are bit-identical to the round-3 passing kernel
// (absmax 0.0): t0..t7 map to the old packed accumulators' .x/.y lanes.

namespace {
constexpr int LSEQ = 256;

__device__ __forceinline__ float RL(float v, int k) {   // broadcast lane k
    return __uint_as_float(__builtin_amdgcn_readlane(__float_as_uint(v), k));
}
#define LDSFENCE() asm volatile("" ::: "memory")
#define KEEPF(x)   asm volatile("" : "+v"(x))   // opaque: forbids remat/fold

__device__ __forceinline__ float tanh_f(float x) {
    float e = exp2f(x * 2.8853900817779268f);
    return 1.0f - 2.0f * __builtin_amdgcn_rcpf(e + 1.0f);
}
__device__ __forceinline__ float sigm_f(float x) {
    return __builtin_amdgcn_rcpf(1.0f + exp2f(x * -1.4426950408889634f));
}
} // namespace

// 64-wide dot vs register weight row; act reads are uniform LDS broadcasts.
// t0..t7 reproduce r3's packed accumulators: tK takes elements c == K (mod 8);
// result = ((t0+t2)+(t4+t6)) + ((t1+t3)+(t5+t7))  ==  old (a0+a1)+(a2+a3),.x+.y
#define DOT64R(res, warr, act, bias)                                   \
    do {                                                               \
        float t0 = (bias), t1 = 0.f, t2 = 0.f, t3 = 0.f,               \
              t4 = 0.f, t5 = 0.f, t6 = 0.f, t7 = 0.f;                  \
        _Pragma("unroll")                                              \
        for (int q = 0; q < 16; q += 2) {                              \
            float4 u = (act)[q];                                       \
            t0 = fmaf(warr[4*q+0], u.x, t0);                           \
            t1 = fmaf(warr[4*q+1], u.y, t1);                           \
            t2 = fmaf(warr[4*q+2], u.z, t2);                           \
            t3 = fmaf(warr[4*q+3], u.w, t3);                           \
            float4 v = (act)[q+1];                                     \
            t4 = fmaf(warr[4*q+4], v.x, t4);                           \
            t5 = fmaf(warr[4*q+5], v.y, t5);                           \
            t6 = fmaf(warr[4*q+6], v.z, t6);                           \
            t7 = fmaf(warr[4*q+7], v.w, t7);                           \
        }                                                              \
        res = ((t0 + t2) + (t4 + t6)) + ((t1 + t3) + (t5 + t7));       \
    } while (0)

// 16-wide dot (L3 split-k chunk); uK takes elements c == K (mod 4);
// result = (u0+u2)+(u1+u3)  ==  old packed (a0+a1).x + .y
#define DOT16R(res, warr, act)                                         \
    do {                                                               \
        float u0 = 0.f, u1 = 0.f, u2 = 0.f, u3 = 0.f;                  \
        _Pragma("unroll")                                              \
        for (int q = 0; q < 4; ++q) {                                  \
            float4 u = (act)[q];                                       \
            u0 = fmaf(warr[4*q+0], u.x, u0);                           \
            u1 = fmaf(warr[4*q+1], u.y, u1);                           \
            u2 = fmaf(warr[4*q+2], u.z, u2);                           \
            u3 = fmaf(warr[4*q+3], u.w, u3);                           \
        }                                                              \
        res = (u0 + u2) + (u1 + u3);                                   \
    } while (0)

extern "C" __global__ void __launch_bounds__(64)
__attribute__((amdgpu_waves_per_eu(1, 1)))
odern_kernel(const float* __restrict__ x_seq,
             const float* __restrict__ W0, const float* __restrict__ b0,
             const float* __restrict__ W1, const float* __restrict__ b1,
             const float* __restrict__ W2, const float* __restrict__ b2,
             const float* __restrict__ W3, const float* __restrict__ b3,
             const float* __restrict__ Wih, const float* __restrict__ Whh,
             const float* __restrict__ bih, const float* __restrict__ bn,
             const float* __restrict__ Wp, const float* __restrict__ bp,
             float* __restrict__ out)
{
    const int j   = threadIdx.x;      // 0..63
    const int b   = blockIdx.x;       // sample
    const int i16 = j & 15;           // owned y-component (replicated x4)

    __shared__ __align__(16) float s_hA[64];
    __shared__ __align__(16) float s_hB[64];
    __shared__ __align__(16) float s_x[2 * LSEQ];
    __shared__ float s_ig[48];
    __shared__ float s_hg[48];

    // ---------------- x row -> LDS (once) ----------------
    {
        const float4* xv = (const float4*)(x_seq + (long)b * (2 * LSEQ));
        float4 t0 = xv[j];
        float4 t1 = xv[j + 64];
        ((float4*)s_x)[j]      = t0;
        ((float4*)s_x)[j + 64] = t1;
    }

    // ---------------- weights -> registers, PINNED ----------------
    float w0s[16], w1s[64], w2s[64], w3s[16], whs[16];
    {
        const float4* p = (const float4*)(W0 + j * 16);
        #pragma unroll
        for (int q = 0; q < 4; ++q) { float4 u = p[q];
            w0s[4*q]=u.x; w0s[4*q+1]=u.y; w0s[4*q+2]=u.z; w0s[4*q+3]=u.w; }
    }
    {
        const float4* p = (const float4*)(W1 + j * 64);
        #pragma unroll
        for (int q = 0; q < 16; ++q) { float4 u = p[q];
            w1s[4*q]=u.x; w1s[4*q+1]=u.y; w1s[4*q+2]=u.z; w1s[4*q+3]=u.w; }
    }
    {
        const float4* p = (const float4*)(W2 + j * 64);
        #pragma unroll
        for (int q = 0; q < 16; ++q) { float4 u = p[q];
            w2s[4*q]=u.x; w2s[4*q+1]=u.y; w2s[4*q+2]=u.z; w2s[4*q+3]=u.w; }
    }
    {
        const float4* p = (const float4*)(W3 + i16 * 64 + (j >> 4) * 16);
        #pragma unroll
        for (int q = 0; q < 4; ++q) { float4 u = p[q];
            w3s[4*q]=u.x; w3s[4*q+1]=u.y; w3s[4*q+2]=u.z; w3s[4*q+3]=u.w; }
    }
    const int jg = (j < 48) ? j : 47;   // clamp for 48-row GRU mats
    {
        const float4* p = (const float4*)(Whh + jg * 16);
        #pragma unroll
        for (int q = 0; q < 4; ++q) { float4 u = p[q];
            whs[4*q]=u.x; whs[4*q+1]=u.y; whs[4*q+2]=u.z; whs[4*q+3]=u.w; }
    }
    float wih0 = Wih[jg * 2], wih1 = Wih[jg * 2 + 1], bihj = bih[jg];
    float bs0 = b0[j], bs1 = b1[j], bs2 = b2[j];
    float b3r = b3[i16], bnr = bn[i16], wpr = Wp[i16];

    // Opaque identity on every loop-invariant value: the compiler can no
    // longer rematerialize the loads inside the hot loop -> true residency.
    #pragma unroll
    for (int i = 0; i < 16; ++i) KEEPF(w0s[i]);
    #pragma unroll
    for (int i = 0; i < 64; ++i) KEEPF(w1s[i]);
    #pragma unroll
    for (int i = 0; i < 64; ++i) KEEPF(w2s[i]);
    #pragma unroll
    for (int i = 0; i < 16; ++i) KEEPF(w3s[i]);
    #pragma unroll
    for (int i = 0; i < 16; ++i) KEEPF(whs[i]);
    KEEPF(wih0); KEEPF(wih1); KEEPF(bihj);
    KEEPF(bs0);  KEEPF(bs1);  KEEPF(bs2);
    KEEPF(b3r);  KEEPF(bnr);  KEEPF(wpr);

    __syncthreads();   // one-time; hot loop is barrier-free

    // MLP eval; ys is lane-replicated (lane k<16 holds component k).
    auto mlp = [&](float ys) -> float {
        // L0: 16 -> 64 via readlane broadcasts (no LDS round-trip).
        float t0 = bs0, t1 = 0.f, t2 = 0.f, t3 = 0.f;
        #pragma unroll
        for (int k = 0; k < 16; k += 4) {
            t0 = fmaf(w0s[k + 0], RL(ys, k + 0), t0);
            t1 = fmaf(w0s[k + 1], RL(ys, k + 1), t1);
            t2 = fmaf(w0s[k + 2], RL(ys, k + 2), t2);
            t3 = fmaf(w0s[k + 3], RL(ys, k + 3), t3);
        }
        float a = tanh_f((t0 + t2) + (t1 + t3));
        s_hA[j] = a;
        LDSFENCE();                 // same-wave DS in-order; stop IR reorder
        float d1; DOT64R(d1, w1s, (const float4*)s_hA, bs1);
        float a1 = tanh_f(d1);
        s_hB[j] = a1;
        LDSFENCE();
        float d2; DOT64R(d2, w2s, (const float4*)s_hB, bs2);
        float a2 = tanh_f(d2);
        s_hA[j] = a2;
        LDSFENCE();
        float p; DOT16R(p, w3s, (const float4*)s_hA + (j >> 4) * 4);
        p += __shfl_xor(p, 16);
        p += __shfl_xor(p, 32);
        LDSFENCE();
        return p + b3r;
    };

    // Tsit5 tableau (f32)
    const float A21 = 0.161f;
    const float A31 = -0.008480655492356989f, A32 = 0.335480655492357f;
    const float A41 = 2.8971530571054935f, A42 = -6.359448489975075f, A43 = 4.3622954328695815f;
    const float A51 = 5.325864828439257f, A52 = -11.748883564062828f, A53 = 7.4955393428898365f, A54 = -0.09249506636175525f;
    const float A61 = 5.86145544294642f, A62 = -12.92096931784711f, A63 = 8.159367898576159f, A64 = -0.071584973281401f, A65 = -0.028269050394068383f;
    const float B1 = 0.09646076681806523f, B2 = 0.01f, B3 = 0.4798896504144996f,
                B4 = 1.379008574103742f, B5 = -3.290069515436081f, B6 = 2.324710524099774f;
    const float E1 = -0.00178001105222577714f, E2 = -0.0008164344596567469f,
                E3 = 0.007880878010261995f, E4 = -0.1447110071732629f,
                E5 = 0.5823571654525552f, E6 = -0.45808210592918697f, E7 = 0.015151515151515152f;
    const float TDONE = (float)(1.0 - 1e-7);

    float y = 0.0f;                       // h0 = zeros (replicated component i16)

    #pragma unroll 1
    for (int l = 0; l < LSEQ; ++l) {
        // ---------------- adaptive Tsit5 on [0,1], dt0 = 1, FSAL ----------
        float t = 0.f, dt = 1.f;
        float k1 = mlp(y);                // first eval of this solve
        #pragma unroll 1
        for (int it = 0; it < 12; ++it) {
            if (t >= TDONE) break;        // identical to reference's frozen iters
            float dtc = fminf(dt, 1.0f - t);
            float k2 = mlp(fmaf(dtc, A21 * k1, y));
            float k3 = mlp(fmaf(dtc, A31*k1 + A32*k2, y));
            float k4 = mlp(fmaf(dtc, A41*k1 + A42*k2 + A43*k3, y));
            float k5 = mlp(fmaf(dtc, A51*k1 + A52*k2 + A53*k3 + A54*k4, y));
            float k6 = mlp(fmaf(dtc, A61*k1 + A62*k2 + A63*k3 + A64*k4 + A65*k5, y));
            float ynew = fmaf(dtc, B1*k1 + B2*k2 + B3*k3 + B4*k4 + B5*k5 + B6*k6, y);
            float k7 = mlp(ynew);
            float yerr = dtc * (E1*k1 + E2*k2 + E3*k3 + E4*k4 + E5*k5 + E6*k6 + E7*k7);
            float sc = fmaf(0.01f, fmaxf(fabsf(y), fabsf(ynew)), 1e-4f);
            float e = yerr / sc;          // keep IEEE: feeds the accept branch
            float e2 = e * e;
            e2 += __shfl_xor(e2, 1); e2 += __shfl_xor(e2, 2);
            e2 += __shfl_xor(e2, 4); e2 += __shfl_xor(e2, 8);
            float err = sqrtf(e2 * 0.0625f);
            if (err <= 1.0f) { y = ynew; t += dtc; k1 = k7; }  // FSAL
            float fac = 0.9f * exp2f(-0.2f * log2f(fmaxf(err, 1e-10f)));
            fac = fminf(fmaxf(fac, 0.2f), 10.0f);
            dt = dtc * fac;
        }
        // ---------------- GRU observation update ----------------
        float x0 = s_x[2*l], x1 = s_x[2*l + 1];
        // hg = Whh[jg,:] . y via readlane (same summation order as before)
        float h0 = 0.f, h1 = 0.f, h2 = 0.f, h3 = 0.f;
        #pragma unroll
        for (int k = 0; k < 16; k += 4) {
            h0 = fmaf(whs[k + 0], RL(y, k + 0), h0);
            h1 = fmaf(whs[k + 1], RL(y, k + 1), h1);
            h2 = fmaf(whs[k + 2], RL(y, k + 2), h2);
            h3 = fmaf(whs[k + 3], RL(y, k + 3), h3);
        }
        float hg = (h0 + h2) + (h1 + h3);
        float ig = fmaf(wih0, x0, fmaf(wih1, x1, bihj));
        if (j < 48) { s_ig[j] = ig; s_hg[j] = hg; }
        LDSFENCE();
        float ir = s_ig[i16], iz = s_ig[16+i16], in_ = s_ig[32+i16];
        float hr = s_hg[i16], hz = s_hg[16+i16], hn = s_hg[32+i16];
        float r = sigm_f(ir + hr);
        float z = sigm_f(iz + hz);
        float n = tanh_f(fmaf(r, hn + bnr, in_));
        y = n + z * (y - n);
        LDSFENCE();
    }

    // ---------------- projection: out[b] = Wp . h + bp ----------------
    float pv = y * wpr;
    pv += __shfl_xor(pv, 1); pv += __shfl_xor(pv, 2);
    pv += __shfl_xor(pv, 4); pv += __shfl_xor(pv, 8);
    if (j == 0) out[b] = pv + bp[0];
}

extern "C" void kernel_launch(void* const* d_in, const int* in_sizes, int n_in,
                              void* d_out, int out_size, void* d_ws, size_t ws_size,
                              hipStream_t stream)
{
    odern_kernel<<<dim3(512), dim3(64), 0, stream>>>(
        (const float*)d_in[0],
        (const float*)d_in[1],  (const float*)d_in[2],
        (const float*)d_in[3],  (const float*)d_in[4],
        (const float*)d_in[5],  (const float*)d_in[6],
        (const float*)d_in[7],  (const float*)d_in[8],
        (const float*)d_in[9],  (const float*)d_in[10],
        (const float*)d_in[11], (const float*)d_in[12],
        (const float*)d_in[13], (const float*)d_in[14],
        (float*)d_out);
}

// Round 9
// 1601.504 us; speedup vs baseline: 1.2145x; 1.2145x over previous
//
#include <hip/hip_runtime.h>
#include <math.h>

// ODE-RNN encoder, fully fused: one 64-lane wave per batch sample.
// Cost model (from r3 counters): ~1792 MLP evals/sample (solver accepts dt=1
// first try), ~2200 cy/eval of which ~1900 is stalls caused by the 4
// per-layer __syncthreads (each drains vmcnt/lgkmcnt -> weight-load latency
// serialized per layer). This round recombines the proven winners:
//  - r3's packed f32x2 dots (v_pk_fma) + global-remat weights (L1-resident;
//    r5 proved LDS weights saturate the LDS pipe, r6 proved KEEPF spills).
//  - r5/r6's barrier-free hot loop (single-wave block: same-wave DS ops are
//    in program order; asm memory clobber stops compiler reordering) ->
//    weight loads stay in flight across layers.
//  - r6's readlane L0/GRU gathers (no LDS round-trip for 16-wide dots).
//  - FSAL (saves a re-eval on rejected steps; free).
// All summation orders bit-match the absmax-0.0 kernels (r3/r5/r6).

namespace {
constexpr int LSEQ = 256;

typedef float f32x2 __attribute__((ext_vector_type(2)));

__device__ __forceinline__ f32x2 mk2(float a, float b) {
    f32x2 r; r.x = a; r.y = b; return r;
}
__device__ __forceinline__ f32x2 fma2(f32x2 a, f32x2 b, f32x2 c) {
    return __builtin_elementwise_fma(a, b, c);
}
__device__ __forceinline__ float RL(float v, int k) {   // broadcast lane k
    return __uint_as_float(__builtin_amdgcn_readlane(__float_as_uint(v), k));
}
#define LDSFENCE() asm volatile("" ::: "memory")

__device__ __forceinline__ float tanh_f(float x) {
    float e = exp2f(x * 2.8853900817779268f);
    return 1.0f - 2.0f * __builtin_amdgcn_rcpf(e + 1.0f);
}
__device__ __forceinline__ float sigm_f(float x) {
    return __builtin_amdgcn_rcpf(1.0f + exp2f(x * -1.4426950408889634f));
}
} // namespace

extern "C" __global__ void __launch_bounds__(64, 1)
odern_kernel(const float* __restrict__ x_seq,
             const float* __restrict__ W0, const float* __restrict__ b0,
             const float* __restrict__ W1, const float* __restrict__ b1,
             const float* __restrict__ W2, const float* __restrict__ b2,
             const float* __restrict__ W3, const float* __restrict__ b3,
             const float* __restrict__ Wih, const float* __restrict__ Whh,
             const float* __restrict__ bih, const float* __restrict__ bn,
             const float* __restrict__ Wp, const float* __restrict__ bp,
             float* __restrict__ out)
{
    const int j   = threadIdx.x;      // 0..63
    const int b   = blockIdx.x;       // sample
    const int i16 = j & 15;           // owned y-component (replicated x4)

    __shared__ __align__(16) float s_hA[64];
    __shared__ __align__(16) float s_hB[64];
    __shared__ __align__(16) float s_x[2 * LSEQ];
    __shared__ float s_ig[48];
    __shared__ float s_hg[48];

    // ---------------- x row -> LDS (once) ----------------
    {
        const float4* xv = (const float4*)(x_seq + (long)b * (2 * LSEQ));
        float4 t0 = xv[j];
        float4 t1 = xv[j + 64];
        ((float4*)s_x)[j]      = t0;
        ((float4*)s_x)[j + 64] = t1;
    }

    // ---------------- weights (plain locals; compiler remats from L1) ----
    float w0s[16], whs[16];
    f32x2 w1v[32], w2v[32], w3v[8];
    {
        const float4* p = (const float4*)(W0 + j * 16);
        #pragma unroll
        for (int q = 0; q < 4; ++q) { float4 u = p[q];
            w0s[4*q]=u.x; w0s[4*q+1]=u.y; w0s[4*q+2]=u.z; w0s[4*q+3]=u.w; }
    }
    {
        const float4* p = (const float4*)(W1 + j * 64);
        #pragma unroll
        for (int q = 0; q < 16; ++q) { float4 u = p[q];
            w1v[2*q] = mk2(u.x, u.y); w1v[2*q+1] = mk2(u.z, u.w); }
    }
    {
        const float4* p = (const float4*)(W2 + j * 64);
        #pragma unroll
        for (int q = 0; q < 16; ++q) { float4 u = p[q];
            w2v[2*q] = mk2(u.x, u.y); w2v[2*q+1] = mk2(u.z, u.w); }
    }
    {
        const float4* p = (const float4*)(W3 + i16 * 64 + (j >> 4) * 16);
        #pragma unroll
        for (int q = 0; q < 4; ++q) { float4 u = p[q];
            w3v[2*q] = mk2(u.x, u.y); w3v[2*q+1] = mk2(u.z, u.w); }
    }
    const int jg = (j < 48) ? j : 47;   // clamp for 48-row GRU mats
    {
        const float4* p = (const float4*)(Whh + jg * 16);
        #pragma unroll
        for (int q = 0; q < 4; ++q) { float4 u = p[q];
            whs[4*q]=u.x; whs[4*q+1]=u.y; whs[4*q+2]=u.z; whs[4*q+3]=u.w; }
    }
    const float wih0 = Wih[jg * 2], wih1 = Wih[jg * 2 + 1], bihj = bih[jg];
    const float bs0 = b0[j], bs1 = b1[j], bs2 = b2[j];
    const float b3r = b3[i16], bnr = bn[i16], wpr = Wp[i16];

    __syncthreads();   // one-time: staging visible; hot loop is barrier-free

    // 64-wide dot: 4 packed accumulators (v_pk_fma), chain order == r3.
    auto dot64 = [&](const float4* p4, const f32x2* wv, float bias) -> float {
        f32x2 a0 = mk2(bias, 0.f), a1 = mk2(0.f, 0.f),
              a2 = mk2(0.f, 0.f),  a3 = mk2(0.f, 0.f);
        #pragma unroll
        for (int q = 0; q < 16; q += 2) {
            float4 u = p4[q];
            a0 = fma2(wv[2*q],   mk2(u.x, u.y), a0);
            a1 = fma2(wv[2*q+1], mk2(u.z, u.w), a1);
            float4 v = p4[q+1];
            a2 = fma2(wv[2*q+2], mk2(v.x, v.y), a2);
            a3 = fma2(wv[2*q+3], mk2(v.z, v.w), a3);
        }
        f32x2 s = (a0 + a1) + (a2 + a3);
        return s.x + s.y;
    };
    // L3 16-wide packed dot (split-k chunk), order == r3.
    auto dot16pk = [&](const float4* p4, const f32x2* wv) -> float {
        f32x2 a0 = mk2(0.f, 0.f), a1 = mk2(0.f, 0.f);
        float4 u = p4[0];
        a0 = fma2(wv[0], mk2(u.x, u.y), a0);
        a1 = fma2(wv[1], mk2(u.z, u.w), a1);
        float4 v = p4[1];
        a0 = fma2(wv[2], mk2(v.x, v.y), a0);
        a1 = fma2(wv[3], mk2(v.z, v.w), a1);
        float4 w = p4[2];
        a0 = fma2(wv[4], mk2(w.x, w.y), a0);
        a1 = fma2(wv[5], mk2(w.z, w.w), a1);
        float4 z = p4[3];
        a0 = fma2(wv[6], mk2(z.x, z.y), a0);
        a1 = fma2(wv[7], mk2(z.z, z.w), a1);
        f32x2 s = a0 + a1;
        return s.x + s.y;
    };

    // MLP eval; ys is lane-replicated (lane k<16 holds component k).
    auto mlp = [&](float ys) -> float {
        // L0: 16 -> 64 via readlane broadcasts (no LDS round-trip).
        float t0 = bs0, t1 = 0.f, t2 = 0.f, t3 = 0.f;
        #pragma unroll
        for (int k = 0; k < 16; k += 4) {
            t0 = fmaf(w0s[k + 0], RL(ys, k + 0), t0);
            t1 = fmaf(w0s[k + 1], RL(ys, k + 1), t1);
            t2 = fmaf(w0s[k + 2], RL(ys, k + 2), t2);
            t3 = fmaf(w0s[k + 3], RL(ys, k + 3), t3);
        }
        float a = tanh_f((t0 + t2) + (t1 + t3));
        s_hA[j] = a;
        LDSFENCE();                 // same-wave DS in-order; stop IR reorder
        float a1 = tanh_f(dot64((const float4*)s_hA, w1v, bs1));
        s_hB[j] = a1;
        LDSFENCE();
        float a2 = tanh_f(dot64((const float4*)s_hB, w2v, bs2));
        s_hA[j] = a2;
        LDSFENCE();
        float p = dot16pk((const float4*)s_hA + (j >> 4) * 4, w3v);
        p += __shfl_xor(p, 16);
        p += __shfl_xor(p, 32);
        LDSFENCE();
        return p + b3r;
    };

    // Tsit5 tableau (f32)
    const float A21 = 0.161f;
    const float A31 = -0.008480655492356989f, A32 = 0.335480655492357f;
    const float A41 = 2.8971530571054935f, A42 = -6.359448489975075f, A43 = 4.3622954328695815f;
    const float A51 = 5.325864828439257f, A52 = -11.748883564062828f, A53 = 7.4955393428898365f, A54 = -0.09249506636175525f;
    const float A61 = 5.86145544294642f, A62 = -12.92096931784711f, A63 = 8.159367898576159f, A64 = -0.071584973281401f, A65 = -0.028269050394068383f;
    const float B1 = 0.09646076681806523f, B2 = 0.01f, B3 = 0.4798896504144996f,
                B4 = 1.379008574103742f, B5 = -3.290069515436081f, B6 = 2.324710524099774f;
    const float E1 = -0.00178001105222577714f, E2 = -0.0008164344596567469f,
                E3 = 0.007880878010261995f, E4 = -0.1447110071732629f,
                E5 = 0.5823571654525552f, E6 = -0.45808210592918697f, E7 = 0.015151515151515152f;
    const float TDONE = (float)(1.0 - 1e-7);

    float y = 0.0f;                       // h0 = zeros (replicated component i16)

    #pragma unroll 1
    for (int l = 0; l < LSEQ; ++l) {
        // ---------------- adaptive Tsit5 on [0,1], dt0 = 1, FSAL ----------
        float t = 0.f, dt = 1.f;
        float k1 = mlp(y);                // first eval of this solve
        #pragma unroll 1
        for (int it = 0; it < 12; ++it) {
            if (t >= TDONE) break;        // identical to reference's frozen iters
            float dtc = fminf(dt, 1.0f - t);
            float k2 = mlp(fmaf(dtc, A21 * k1, y));
            float k3 = mlp(fmaf(dtc, A31*k1 + A32*k2, y));
            float k4 = mlp(fmaf(dtc, A41*k1 + A42*k2 + A43*k3, y));
            float k5 = mlp(fmaf(dtc, A51*k1 + A52*k2 + A53*k3 + A54*k4, y));
            float k6 = mlp(fmaf(dtc, A61*k1 + A62*k2 + A63*k3 + A64*k4 + A65*k5, y));
            float ynew = fmaf(dtc, B1*k1 + B2*k2 + B3*k3 + B4*k4 + B5*k5 + B6*k6, y);
            float k7 = mlp(ynew);
            float yerr = dtc * (E1*k1 + E2*k2 + E3*k3 + E4*k4 + E5*k5 + E6*k6 + E7*k7);
            float sc = fmaf(0.01f, fmaxf(fabsf(y), fabsf(ynew)), 1e-4f);
            float e = yerr / sc;          // keep IEEE: feeds the accept branch
            float e2 = e * e;
            e2 += __shfl_xor(e2, 1); e2 += __shfl_xor(e2, 2);
            e2 += __shfl_xor(e2, 4); e2 += __shfl_xor(e2, 8);
            float err = sqrtf(e2 * 0.0625f);
            if (err <= 1.0f) { y = ynew; t += dtc; k1 = k7; }  // FSAL
            float fac = 0.9f * exp2f(-0.2f * log2f(fmaxf(err, 1e-10f)));
            fac = fminf(fmaxf(fac, 0.2f), 10.0f);
            dt = dtc * fac;
        }
        // ---------------- GRU observation update ----------------
        float x0 = s_x[2*l], x1 = s_x[2*l + 1];
        // hg = Whh[jg,:] . y via readlane (same summation order as before)
        float h0 = 0.f, h1 = 0.f, h2 = 0.f, h3 = 0.f;
        #pragma unroll
        for (int k = 0; k < 16; k += 4) {
            h0 = fmaf(whs[k + 0], RL(y, k + 0), h0);
            h1 = fmaf(whs[k + 1], RL(y, k + 1), h1);
            h2 = fmaf(whs[k + 2], RL(y, k + 2), h2);
            h3 = fmaf(whs[k + 3], RL(y, k + 3), h3);
        }
        float hg = (h0 + h2) + (h1 + h3);
        float ig = fmaf(wih0, x0, fmaf(wih1, x1, bihj));
        if (j < 48) { s_ig[j] = ig; s_hg[j] = hg; }
        LDSFENCE();
        float ir = s_ig[i16], iz = s_ig[16+i16], in_ = s_ig[32+i16];
        float hr = s_hg[i16], hz = s_hg[16+i16], hn = s_hg[32+i16];
        float r = sigm_f(ir + hr);
        float z = sigm_f(iz + hz);
        float n = tanh_f(fmaf(r, hn + bnr, in_));
        y = n + z * (y - n);
        LDSFENCE();
    }

    // ---------------- projection: out[b] = Wp . h + bp ----------------
    float pv = y * wpr;
    pv += __shfl_xor(pv, 1); pv += __shfl_xor(pv, 2);
    pv += __shfl_xor(pv, 4); pv += __shfl_xor(pv, 8);
    if (j == 0) out[b] = pv + bp[0];
}

extern "C" void kernel_launch(void* const* d_in, const int* in_sizes, int n_in,
                              void* d_out, int out_size, void* d_ws, size_t ws_size,
                              hipStream_t stream)
{
    odern_kernel<<<dim3(512), dim3(64), 0, stream>>>(
        (const float*)d_in[0],
        (const float*)d_in[1],  (const float*)d_in[2],
        (const float*)d_in[3],  (const float*)d_in[4],
        (const float*)d_in[5],  (const float*)d_in[6],
        (const float*)d_in[7],  (const float*)d_in[8],
        (const float*)d_in[9],  (const float*)d_in[10],
        (const float*)d_in[11], (const float*)d_in[12],
        (const float*)d_in[13], (const float*)d_in[14],
        (float*)d_out);
}

// Round 10
// 1483.640 us; speedup vs baseline: 1.3110x; 1.0794x over previous
//
#include <hip/hip_runtime.h>
#include <math.h>

// ODE-RNN encoder, fully fused: one 64-lane wave per batch sample.
// Cost model (r9 counters): ~1792 evals/sample, ~2150 cy/eval, only ~380 cy
// VALU issue. Diagnosis: W1+W2 (32KB) are remat-loaded from global EVERY eval
// (VGPR=120 across r3/r6/r8/r9 = RA refuses residency); working set ~36KB >
// 32KB L1 -> thrash -> ~36 L2-latency loads/eval ≈ the missing ~1800 cy.
// Fix: W1/W2 live in LDS (stride-68 rows: bank start rotates 4/row, inherent
// 8-phase b128 only), and dot64 uses an explicit 2-ahead software pipeline so
// LDS latency overlaps FMA issue (r5 failed here: serial read->FMA pairs).
// FMA summation order is BIT-IDENTICAL to r9's absmax-0.0 kernel.
// Remaining globals (W0/W3/Whh/x ≈ 10KB) now fit L1.
//  - FSAL, readlane L0/GRU gathers, barrier-free single-wave hot loop kept.

namespace {
constexpr int LSEQ = 256;
constexpr int WSTR = 68;   // LDS weight row stride in dwords (64 + 4 pad)

typedef float f32x2 __attribute__((ext_vector_type(2)));

__device__ __forceinline__ f32x2 mk2(float a, float b) {
    f32x2 r; r.x = a; r.y = b; return r;
}
__device__ __forceinline__ f32x2 fma2(f32x2 a, f32x2 b, f32x2 c) {
    return __builtin_elementwise_fma(a, b, c);
}
__device__ __forceinline__ float RL(float v, int k) {   // broadcast lane k
    return __uint_as_float(__builtin_amdgcn_readlane(__float_as_uint(v), k));
}
#define LDSFENCE() asm volatile("" ::: "memory")

__device__ __forceinline__ float tanh_f(float x) {
    float e = exp2f(x * 2.8853900817779268f);
    return 1.0f - 2.0f * __builtin_amdgcn_rcpf(e + 1.0f);
}
__device__ __forceinline__ float sigm_f(float x) {
    return __builtin_amdgcn_rcpf(1.0f + exp2f(x * -1.4426950408889634f));
}
} // namespace

extern "C" __global__ void __launch_bounds__(64, 1)
odern_kernel(const float* __restrict__ x_seq,
             const float* __restrict__ W0, const float* __restrict__ b0,
             const float* __restrict__ W1, const float* __restrict__ b1,
             const float* __restrict__ W2, const float* __restrict__ b2,
             const float* __restrict__ W3, const float* __restrict__ b3,
             const float* __restrict__ Wih, const float* __restrict__ Whh,
             const float* __restrict__ bih, const float* __restrict__ bn,
             const float* __restrict__ Wp, const float* __restrict__ bp,
             float* __restrict__ out)
{
    const int j   = threadIdx.x;      // 0..63
    const int b   = blockIdx.x;       // sample
    const int i16 = j & 15;           // owned y-component (replicated x4)

    __shared__ __align__(16) float s_w1[64 * WSTR];  // W1 rows, stride 68
    __shared__ __align__(16) float s_w2[64 * WSTR];  // W2 rows, stride 68
    __shared__ __align__(16) float s_hA[64];
    __shared__ __align__(16) float s_hB[64];
    __shared__ __align__(16) float s_x[2 * LSEQ];
    __shared__ float s_ig[48];
    __shared__ float s_hg[48];

    // ---------------- x row -> LDS (once) ----------------
    {
        const float4* xv = (const float4*)(x_seq + (long)b * (2 * LSEQ));
        float4 t0 = xv[j];
        float4 t1 = xv[j + 64];
        ((float4*)s_x)[j]      = t0;
        ((float4*)s_x)[j + 64] = t1;
    }
    // ---------------- W1/W2 -> LDS (once), stride-68 rows --------------
    {
        const float4* g1 = (const float4*)(W1 + j * 64);
        const float4* g2 = (const float4*)(W2 + j * 64);
        float* r1 = s_w1 + j * WSTR;
        float* r2 = s_w2 + j * WSTR;
        #pragma unroll
        for (int q = 0; q < 16; ++q) {
            *(float4*)(r1 + 4 * q) = g1[q];
            *(float4*)(r2 + 4 * q) = g2[q];
        }
    }

    // ---------------- small weights (L1-resident remat is fine) --------
    float w0s[16], whs[16];
    f32x2 w3v[8];
    {
        const float4* p = (const float4*)(W0 + j * 16);
        #pragma unroll
        for (int q = 0; q < 4; ++q) { float4 u = p[q];
            w0s[4*q]=u.x; w0s[4*q+1]=u.y; w0s[4*q+2]=u.z; w0s[4*q+3]=u.w; }
    }
    {
        const float4* p = (const float4*)(W3 + i16 * 64 + (j >> 4) * 16);
        #pragma unroll
        for (int q = 0; q < 4; ++q) { float4 u = p[q];
            w3v[2*q] = mk2(u.x, u.y); w3v[2*q+1] = mk2(u.z, u.w); }
    }
    const int jg = (j < 48) ? j : 47;   // clamp for 48-row GRU mats
    {
        const float4* p = (const float4*)(Whh + jg * 16);
        #pragma unroll
        for (int q = 0; q < 4; ++q) { float4 u = p[q];
            whs[4*q]=u.x; whs[4*q+1]=u.y; whs[4*q+2]=u.z; whs[4*q+3]=u.w; }
    }
    const float wih0 = Wih[jg * 2], wih1 = Wih[jg * 2 + 1], bihj = bih[jg];
    const float bs0 = b0[j], bs1 = b1[j], bs2 = b2[j];
    const float b3r = b3[i16], bnr = bn[i16], wpr = Wp[i16];

    __syncthreads();   // one-time: staging visible; hot loop is barrier-free

    // 64-wide dot: weights from LDS row (per-lane), acts uniform broadcast.
    // 2-iteration-ahead software pipeline; summation order == r9 (bit-exact):
    //   q even pair -> a0(w.xy*u.xy), a1(w.zw*u.zw); odd -> a2, a3.
    auto dot64 = [&](const float* wrow, const float4* act, float bias) -> float {
        f32x2 a0 = mk2(bias, 0.f), a1 = mk2(0.f, 0.f),
              a2 = mk2(0.f, 0.f),  a3 = mk2(0.f, 0.f);
        float4 wa = *(const float4*)(wrow + 0);
        float4 ua = act[0];
        float4 wb = *(const float4*)(wrow + 4);
        float4 ub = act[1];
        #pragma unroll
        for (int q = 0; q < 16; q += 2) {
            float4 wc, uc, wd, ud;
            if (q < 14) {
                wc = *(const float4*)(wrow + 4 * (q + 2));
                uc = act[q + 2];
                wd = *(const float4*)(wrow + 4 * (q + 3));
                ud = act[q + 3];
            }
            a0 = fma2(mk2(wa.x, wa.y), mk2(ua.x, ua.y), a0);
            a1 = fma2(mk2(wa.z, wa.w), mk2(ua.z, ua.w), a1);
            a2 = fma2(mk2(wb.x, wb.y), mk2(ub.x, ub.y), a2);
            a3 = fma2(mk2(wb.z, wb.w), mk2(ub.z, ub.w), a3);
            wa = wc; ua = uc; wb = wd; ub = ud;
        }
        f32x2 s = (a0 + a1) + (a2 + a3);
        return s.x + s.y;
    };
    // L3 16-wide packed dot (split-k chunk), order == r9.
    auto dot16pk = [&](const float4* p4, const f32x2* wv) -> float {
        f32x2 a0 = mk2(0.f, 0.f), a1 = mk2(0.f, 0.f);
        float4 u = p4[0];
        a0 = fma2(wv[0], mk2(u.x, u.y), a0);
        a1 = fma2(wv[1], mk2(u.z, u.w), a1);
        float4 v = p4[1];
        a0 = fma2(wv[2], mk2(v.x, v.y), a0);
        a1 = fma2(wv[3], mk2(v.z, v.w), a1);
        float4 w = p4[2];
        a0 = fma2(wv[4], mk2(w.x, w.y), a0);
        a1 = fma2(wv[5], mk2(w.z, w.w), a1);
        float4 z = p4[3];
        a0 = fma2(wv[6], mk2(z.x, z.y), a0);
        a1 = fma2(wv[7], mk2(z.z, z.w), a1);
        f32x2 s = a0 + a1;
        return s.x + s.y;
    };

    const float* w1row = s_w1 + j * WSTR;
    const float* w2row = s_w2 + j * WSTR;

    // MLP eval; ys is lane-replicated (lane k<16 holds component k).
    auto mlp = [&](float ys) -> float {
        // L0: 16 -> 64 via readlane broadcasts (no LDS round-trip).
        float t0 = bs0, t1 = 0.f, t2 = 0.f, t3 = 0.f;
        #pragma unroll
        for (int k = 0; k < 16; k += 4) {
            t0 = fmaf(w0s[k + 0], RL(ys, k + 0), t0);
            t1 = fmaf(w0s[k + 1], RL(ys, k + 1), t1);
            t2 = fmaf(w0s[k + 2], RL(ys, k + 2), t2);
            t3 = fmaf(w0s[k + 3], RL(ys, k + 3), t3);
        }
        float a = tanh_f((t0 + t2) + (t1 + t3));
        s_hA[j] = a;
        LDSFENCE();                 // same-wave DS in-order; stop IR reorder
        float a1 = tanh_f(dot64(w1row, (const float4*)s_hA, bs1));
        s_hB[j] = a1;
        LDSFENCE();
        float a2 = tanh_f(dot64(w2row, (const float4*)s_hB, bs2));
        s_hA[j] = a2;
        LDSFENCE();
        float p = dot16pk((const float4*)s_hA + (j >> 4) * 4, w3v);
        p += __shfl_xor(p, 16);
        p += __shfl_xor(p, 32);
        LDSFENCE();
        return p + b3r;
    };

    // Tsit5 tableau (f32)
    const float A21 = 0.161f;
    const float A31 = -0.008480655492356989f, A32 = 0.335480655492357f;
    const float A41 = 2.8971530571054935f, A42 = -6.359448489975075f, A43 = 4.3622954328695815f;
    const float A51 = 5.325864828439257f, A52 = -11.748883564062828f, A53 = 7.4955393428898365f, A54 = -0.09249506636175525f;
    const float A61 = 5.86145544294642f, A62 = -12.92096931784711f, A63 = 8.159367898576159f, A64 = -0.071584973281401f, A65 = -0.028269050394068383f;
    const float B1 = 0.09646076681806523f, B2 = 0.01f, B3 = 0.4798896504144996f,
                B4 = 1.379008574103742f, B5 = -3.290069515436081f, B6 = 2.324710524099774f;
    const float E1 = -0.00178001105222577714f, E2 = -0.0008164344596567469f,
                E3 = 0.007880878010261995f, E4 = -0.1447110071732629f,
                E5 = 0.5823571654525552f, E6 = -0.45808210592918697f, E7 = 0.015151515151515152f;
    const float TDONE = (float)(1.0 - 1e-7);

    float y = 0.0f;                       // h0 = zeros (replicated component i16)

    #pragma unroll 1
    for (int l = 0; l < LSEQ; ++l) {
        // ---------------- adaptive Tsit5 on [0,1], dt0 = 1, FSAL ----------
        float t = 0.f, dt = 1.f;
        float k1 = mlp(y);                // first eval of this solve
        #pragma unroll 1
        for (int it = 0; it < 12; ++it) {
            if (t >= TDONE) break;        // identical to reference's frozen iters
            float dtc = fminf(dt, 1.0f - t);
            float k2 = mlp(fmaf(dtc, A21 * k1, y));
            float k3 = mlp(fmaf(dtc, A31*k1 + A32*k2, y));
            float k4 = mlp(fmaf(dtc, A41*k1 + A42*k2 + A43*k3, y));
            float k5 = mlp(fmaf(dtc, A51*k1 + A52*k2 + A53*k3 + A54*k4, y));
            float k6 = mlp(fmaf(dtc, A61*k1 + A62*k2 + A63*k3 + A64*k4 + A65*k5, y));
            float ynew = fmaf(dtc, B1*k1 + B2*k2 + B3*k3 + B4*k4 + B5*k5 + B6*k6, y);
            float k7 = mlp(ynew);
            float yerr = dtc * (E1*k1 + E2*k2 + E3*k3 + E4*k4 + E5*k5 + E6*k6 + E7*k7);
            float sc = fmaf(0.01f, fmaxf(fabsf(y), fabsf(ynew)), 1e-4f);
            float e = yerr / sc;          // keep IEEE: feeds the accept branch
            float e2 = e * e;
            e2 += __shfl_xor(e2, 1); e2 += __shfl_xor(e2, 2);
            e2 += __shfl_xor(e2, 4); e2 += __shfl_xor(e2, 8);
            float err = sqrtf(e2 * 0.0625f);
            if (err <= 1.0f) { y = ynew; t += dtc; k1 = k7; }  // FSAL
            float fac = 0.9f * exp2f(-0.2f * log2f(fmaxf(err, 1e-10f)));
            fac = fminf(fmaxf(fac, 0.2f), 10.0f);
            dt = dtc * fac;
        }
        // ---------------- GRU observation update ----------------
        float x0 = s_x[2*l], x1 = s_x[2*l + 1];
        // hg = Whh[jg,:] . y via readlane (same summation order as before)
        float h0 = 0.f, h1 = 0.f, h2 = 0.f, h3 = 0.f;
        #pragma unroll
        for (int k = 0; k < 16; k += 4) {
            h0 = fmaf(whs[k + 0], RL(y, k + 0), h0);
            h1 = fmaf(whs[k + 1], RL(y, k + 1), h1);
            h2 = fmaf(whs[k + 2], RL(y, k + 2), h2);
            h3 = fmaf(whs[k + 3], RL(y, k + 3), h3);
        }
        float hg = (h0 + h2) + (h1 + h3);
        float ig = fmaf(wih0, x0, fmaf(wih1, x1, bihj));
        if (j < 48) { s_ig[j] = ig; s_hg[j] = hg; }
        LDSFENCE();
        float ir = s_ig[i16], iz = s_ig[16+i16], in_ = s_ig[32+i16];
        float hr = s_hg[i16], hz = s_hg[16+i16], hn = s_hg[32+i16];
        float r = sigm_f(ir + hr);
        float z = sigm_f(iz + hz);
        float n = tanh_f(fmaf(r, hn + bnr, in_));
        y = n + z * (y - n);
        LDSFENCE();
    }

    // ---------------- projection: out[b] = Wp . h + bp ----------------
    float pv = y * wpr;
    pv += __shfl_xor(pv, 1); pv += __shfl_xor(pv, 2);
    pv += __shfl_xor(pv, 4); pv += __shfl_xor(pv, 8);
    if (j == 0) out[b] = pv + bp[0];
}

extern "C" void kernel_launch(void* const* d_in, const int* in_sizes, int n_in,
                              void* d_out, int out_size, void* d_ws, size_t ws_size,
                              hipStream_t stream)
{
    odern_kernel<<<dim3(512), dim3(64), 0, stream>>>(
        (const float*)d_in[0],
        (const float*)d_in[1],  (const float*)d_in[2],
        (const float*)d_in[3],  (const float*)d_in[4],
        (const float*)d_in[5],  (const float*)d_in[6],
        (const float*)d_in[7],  (const float*)d_in[8],
        (const float*)d_in[9],  (const float*)d_in[10],
        (const float*)d_in[11], (const float*)d_in[12],
        (const float*)d_in[13], (const float*)d_in[14],
        (float*)d_out);
}